// Round 5
// baseline (1128.395 us; speedup 1.0000x reference)
//
#include <hip/hip_runtime.h>
#include <math.h>

#define B    256
#define I    1152
#define O    10
#define DIN  8
#define DOUT 16
#define OE   160          // O*DOUT
#define XROW 9216         // I*DIN (K of the s-GEMM, M of the g-GEMM)
#define WROW 1280         // O*DIN*DOUT (= OE*DIN, Wt row length)
#define PSPLIT 72         // split-K partials
#define CHUNK  16         // i per spart block
#define SI     8          // i per staging round (K-window 64)
#define GRID   288        // 4*PSPLIT blocks; co-residency: 288 <= 256CU*2blk

#define WPREP_JOBS 720    // I*OE/256

typedef __attribute__((ext_vector_type(8))) short short8;
typedef __attribute__((ext_vector_type(4))) float floatx4;

__device__ __forceinline__ unsigned short f2bf(float f) {
    unsigned u = __builtin_bit_cast(unsigned, f);
    u += 0x7fffu + ((u >> 16) & 1u);          // RNE
    return (unsigned short)(u >> 16);
}
__device__ __forceinline__ float bf2f(unsigned short h) {
    unsigned u = ((unsigned)h) << 16;
    return __builtin_bit_cast(float, u);
}

__device__ __forceinline__ void split8(const float* __restrict__ xp,
                                       short8& h8, short8& l8)
{
    float4 v0 = *(const float4*)xp;
    float4 v1 = *(const float4*)(xp + 4);
    float v[8] = {v0.x, v0.y, v0.z, v0.w, v1.x, v1.y, v1.z, v1.w};
#pragma unroll
    for (int d = 0; d < 8; ++d) {
        unsigned short h = f2bf(v[d]);
        h8[d] = (short)h;
        l8[d] = (short)f2bf(v[d] - bf2f(h));
    }
}

// ---------------------------------------------------------------------------
// Software grid barrier (no cooperative API). Generation-based; AGENT-scope
// atomics reach the device coherence point (cross-XCD safe); __threadfence
// release/acquire makes ordinary stores/loads visible across the barrier.
// Failsafe iteration cap: a logic bug fails the test instead of hanging.
// Safety: grid=288 co-resident via __launch_bounds__(256,2) (>=2 blk/CU,
// capacity 512) -- dispatch is resource-driven, all blocks get placed.
// ---------------------------------------------------------------------------
__device__ __forceinline__ void gbar(unsigned* cnt, unsigned* gen)
{
    __threadfence();                               // release prior writes
    __syncthreads();
    if (threadIdx.x == 0) {
        unsigned g = __hip_atomic_load(gen, __ATOMIC_RELAXED, __HIP_MEMORY_SCOPE_AGENT);
        unsigned a = __hip_atomic_fetch_add(cnt, 1u, __ATOMIC_ACQ_REL, __HIP_MEMORY_SCOPE_AGENT);
        if (a == GRID - 1) {
            __hip_atomic_store(cnt, 0u, __ATOMIC_RELAXED, __HIP_MEMORY_SCOPE_AGENT);
            __hip_atomic_store(gen, g + 1u, __ATOMIC_RELEASE, __HIP_MEMORY_SCOPE_AGENT);
        } else {
            int spins = 0;
            while (__hip_atomic_load(gen, __ATOMIC_ACQUIRE, __HIP_MEMORY_SCOPE_AGENT) == g) {
                __builtin_amdgcn_s_sleep(2);
                if (++spins > (1 << 24)) break;    // failsafe, never hit in practice
            }
        }
    }
    __syncthreads();
    __threadfence();                               // acquire side
}

// ---------------------------------------------------------------------------
// STAGE: prep (one-time). W -> Wt[i][oe][d] fp32 (d-contiguous);
// x -> xTh/xTl[(i*8+d)][b] bf16 hi/lo (b-contiguous, g-GEMM A operand).
// ---------------------------------------------------------------------------
__device__ __forceinline__ void stage_prep(
    int bid, int t,
    const float* __restrict__ x, const float* __restrict__ W,
    float* __restrict__ Wt,
    unsigned short* __restrict__ xTh, unsigned short* __restrict__ xTl)
{
#pragma unroll
    for (int r = 0; r < 3; ++r) {
        int job = bid + GRID * r;
        if (job < WPREP_JOBS) {
            int g  = job * 256 + t;               // (i, oe) pair
            int i  = g / OE;
            int oe = g - i * OE;
            int o  = oe >> 4;
            int e  = oe & 15;
            const float* wp = W + (size_t)i * WROW + o * (DIN * DOUT) + e;
            float4 a, b;
            a.x = wp[0 * DOUT]; a.y = wp[1 * DOUT]; a.z = wp[2 * DOUT]; a.w = wp[3 * DOUT];
            b.x = wp[4 * DOUT]; b.y = wp[5 * DOUT]; b.z = wp[6 * DOUT]; b.w = wp[7 * DOUT];
            float4* dst = (float4*)(Wt + (size_t)g * 8);
            dst[0] = a;
            dst[1] = b;
        }
    }
#pragma unroll
    for (int r = 0; r < 4; ++r) {                 // 4*288 = 1152 jobs exactly
        int g2  = bid + GRID * r;
        int idb = g2 % 144;
        int bb  = g2 / 144;
        int id  = idb * 64 + (t & 63);            // (i,d) flat row
        int b0  = bb * 32 + (t >> 6) * 8;         // 8 batch elems per thread
        float v[8];
#pragma unroll
        for (int j = 0; j < 8; ++j)
            v[j] = x[(size_t)(b0 + j) * XROW + id];
        short8 h8, l8;
#pragma unroll
        for (int j = 0; j < 8; ++j) {
            unsigned short h = f2bf(v[j]);
            h8[j] = (short)h;
            l8[j] = (short)f2bf(v[j] - bf2f(h));
        }
        *(short8*)(xTh + (size_t)id * B + b0) = h8;
        *(short8*)(xTl + (size_t)id * B + b0) = l8;
    }
}

// ---------------------------------------------------------------------------
// STAGE: spart (proven R2 GEMM body + R3-style routing prologue).
// it==0: c = 0.1. it>=1: b = (a0 [+ a1])/B recomputed locally, softmax -> cL.
// s[b,oe] = sum_k x[b,k] * (c[i,o]*W)[k,oe]; 3 MFMAs/tile (xl*wl dropped).
// ---------------------------------------------------------------------------
__device__ __forceinline__ void stage_spart(
    int bid, int t,
    unsigned short* __restrict__ Wh, unsigned short* __restrict__ Wl,
    float (*brow_s)[10], float (*cL)[10],
    const float* __restrict__ x, const float* __restrict__ Wt,
    const float* __restrict__ a0, const float* __restrict__ a1,
    float* __restrict__ sp, int it)
{
    int ic  = bid >> 2;
    int mb  = (bid >> 1) & 1;
    int nb  = bid & 1;
    int b0  = mb * 128;
    int oe0 = nb * 80;
    int i0  = ic * CHUNK;

    int w    = t >> 6;
    int lane = t & 63;
    int l15  = lane & 15;
    int q    = lane >> 4;

    // ---- routing prologue: logits from agree partial sums, softmax -> cL ----
    if (it) {
        if (t < 160) {
            int iL = t / 10;
            int o  = t - iL * 10;
            int i  = i0 + iL;
            float bo = a0[i * O + o] * (1.f / (float)B);
            if (it == 2) bo += a1[i * O + o] * (1.f / (float)B);
            brow_s[iL][o] = bo;
        }
        __syncthreads();
        if (t < 16) {
            float m = brow_s[t][0];
#pragma unroll
            for (int o = 1; o < O; ++o) m = fmaxf(m, brow_s[t][o]);
            float ex[O];
            float sum = 0.f;
#pragma unroll
            for (int o = 0; o < O; ++o) { ex[o] = __expf(brow_s[t][o] - m); sum += ex[o]; }
            float inv = 1.f / sum;
#pragma unroll
            for (int o = 0; o < O; ++o) cL[t][o] = ex[o] * inv;
        }
        __syncthreads();
    }

    floatx4 acc[2][5];
#pragma unroll
    for (int mt = 0; mt < 2; ++mt)
#pragma unroll
        for (int nt = 0; nt < 5; ++nt) acc[mt][nt] = (floatx4)(0.f);

#pragma unroll
    for (int round = 0; round < CHUNK / SI; ++round) {
        int si0 = i0 + round * SI;
        if (round) __syncthreads();

        // X fragments: direct global fp32 loads + in-register split
        short8 ah[2][2], al[2][2];                // [ks][mt]
#pragma unroll
        for (int ks = 0; ks < 2; ++ks)
#pragma unroll
            for (int mt = 0; mt < 2; ++mt) {
                const float* xp = x + (size_t)(b0 + w * 32 + mt * 16 + l15) * XROW
                                + (size_t)si0 * 8 + (ks << 5) + (q << 3);
                split8(xp, ah[ks][mt], al[ks][mt]);
            }

        // stage W: coalesced loads from Wt, scale by c, split hi/lo
#pragma unroll
        for (int r = 0; r < 3; ++r) {
            int p = t + 256 * r;                  // (oe-local, i-local) pair
            if (p < 640) {
                int oeL = p % 80;
                int iL  = p / 80;                 // 0..7
                int o   = (oe0 + oeL) >> 4;
                const float* wp = Wt + ((size_t)(si0 + iL) * OE + oe0 + oeL) * 8;
                float cv = it ? cL[round * SI + iL][o] : 0.1f;
                float4 w0 = *(const float4*)wp;
                float4 w1 = *(const float4*)(wp + 4);
                float wv[8] = {w0.x, w0.y, w0.z, w0.w, w1.x, w1.y, w1.z, w1.w};
                short8 hv, lv;
#pragma unroll
                for (int d = 0; d < 8; ++d) {
                    float s = wv[d] * cv;
                    unsigned short h = f2bf(s);
                    hv[d] = (short)h;
                    lv[d] = (short)f2bf(s - bf2f(h));
                }
                int off = oeL * 64 + ((iL ^ (oeL & 7)) << 3);
                *(short8*)(Wh + off) = hv;
                *(short8*)(Wl + off) = lv;
            }
        }
        __syncthreads();

        // 2 K-steps of 32 over the staged window
#pragma unroll
        for (int ks = 0; ks < 2; ++ks) {
#pragma unroll
            for (int nt = 0; nt < 5; ++nt) {
                int rn  = nt * 16 + l15;
                int off = rn * 64 + ((((ks << 2) + q) ^ (rn & 7)) << 3);
                short8 bh = *(const short8*)(Wh + off);
                short8 bl = *(const short8*)(Wl + off);
#pragma unroll
                for (int mt = 0; mt < 2; ++mt) {
                    acc[mt][nt] = __builtin_amdgcn_mfma_f32_16x16x32_bf16(ah[ks][mt], bh, acc[mt][nt], 0, 0, 0);
                    acc[mt][nt] = __builtin_amdgcn_mfma_f32_16x16x32_bf16(ah[ks][mt], bl, acc[mt][nt], 0, 0, 0);
                    acc[mt][nt] = __builtin_amdgcn_mfma_f32_16x16x32_bf16(al[ks][mt], bh, acc[mt][nt], 0, 0, 0);
                }
            }
        }
    }

    // epilogue: C/D layout col=lane&15, row=(lane>>4)*4+reg (m89/m91)
    float* base = sp + (size_t)ic * (B * OE);
#pragma unroll
    for (int mt = 0; mt < 2; ++mt) {
        int row0 = b0 + w * 32 + mt * 16 + q * 4;
#pragma unroll
        for (int nt = 0; nt < 5; ++nt) {
            int col = oe0 + nt * 16 + l15;
#pragma unroll
            for (int reg = 0; reg < 4; ++reg)
                base[(row0 + reg) * OE + col] = acc[mt][nt][reg];
        }
    }
}

// ---------------------------------------------------------------------------
// STAGE: vred. Sum PSPLIT partials + squash; iters 0,1 -> v as bf16 hi/lo
// transposed [oe][b]; iter 2 -> final out. 160 of 288 blocks active.
// ---------------------------------------------------------------------------
__device__ __forceinline__ void stage_vred(
    int bid, int t, const float* __restrict__ sp, float* __restrict__ out,
    unsigned short* __restrict__ vhT, unsigned short* __restrict__ vlT, int last)
{
    if (bid >= 160) return;
    int g = bid * 256 + t;                      // [b][o][e] flat
    float s = 0.f;
#pragma unroll 8
    for (int ic = 0; ic < PSPLIT; ++ic) s += sp[(size_t)ic * (B * OE) + g];

    float ss = s * s;
    ss += __shfl_xor(ss, 1, 16);
    ss += __shfl_xor(ss, 2, 16);
    ss += __shfl_xor(ss, 4, 16);
    ss += __shfl_xor(ss, 8, 16);
    float f = sqrtf(ss) / (1.f + ss);           // squash factor
    float val = s * f;

    if (last) {
        out[g] = val;
    } else {
        int b  = g / OE;
        int oe = g - b * OE;
        unsigned short h = f2bf(val);
        vhT[oe * B + b] = h;
        vlT[oe * B + b] = f2bf(val - bf2f(h));
    }
}

// ---------------------------------------------------------------------------
// STAGE: ggemm + in-wave agree epilogue. G[(i,d)][oe] = sum_b xT*v via MFMA
// (proven R3 body); G never materialized: each 16x16 tile holds 2 i x 8 d,
// agree[i,o] = sum_{d,e} Wt*G reduces via float4-dot + shfl-xor tree.
// 144 of 288 blocks active. Writes raw dot (1/B applied in spart prologue).
// ---------------------------------------------------------------------------
__device__ __forceinline__ void stage_ggemm(
    int bid, int t,
    unsigned short* __restrict__ Vh, unsigned short* __restrict__ Vl,
    const unsigned short* __restrict__ xTh, const unsigned short* __restrict__ xTl,
    const unsigned short* __restrict__ vhT, const unsigned short* __restrict__ vlT,
    const float* __restrict__ Wt, float* __restrict__ agree)
{
    if (bid >= 144) return;
    int m0  = (bid >> 1) * 128;
    int nb  = bid & 1;
    int oe0 = nb * 80;

    int w    = t >> 6;
    int lane = t & 63;
    int l15  = lane & 15;
    int q    = lane >> 4;

    floatx4 acc[2][5];
#pragma unroll
    for (int mt = 0; mt < 2; ++mt)
#pragma unroll
        for (int nt = 0; nt < 5; ++nt) acc[mt][nt] = (floatx4)(0.f);

#pragma unroll
    for (int win = 0; win < 4; ++win) {
        int k0 = win * 64;
        if (win) __syncthreads();

        // stage V window [80 oe][64 b], XOR-swizzled 16B chunks
#pragma unroll
        for (int r = 0; r < 3; ++r) {
            int p = t + 256 * r;
            if (p < 640) {
                int row = p >> 3;
                int ch  = p & 7;
                int off = row * 64 + ((ch ^ (row & 7)) << 3);
                size_t gsrc = (size_t)(oe0 + row) * B + k0 + (ch << 3);
                *(short8*)(Vh + off) = *(const short8*)(vhT + gsrc);
                *(short8*)(Vl + off) = *(const short8*)(vlT + gsrc);
            }
        }
        __syncthreads();

        // A fragments direct from xT (b-contiguous rows)
        short8 ah[2][2], al[2][2];
#pragma unroll
        for (int ks = 0; ks < 2; ++ks)
#pragma unroll
            for (int mt = 0; mt < 2; ++mt) {
                size_t ga = (size_t)(m0 + w * 32 + mt * 16 + l15) * B
                          + k0 + (ks << 5) + (q << 3);
                ah[ks][mt] = *(const short8*)(xTh + ga);
                al[ks][mt] = *(const short8*)(xTl + ga);
            }

#pragma unroll
        for (int ks = 0; ks < 2; ++ks) {
#pragma unroll
            for (int nt = 0; nt < 5; ++nt) {
                int rn  = nt * 16 + l15;
                int off = rn * 64 + ((((ks << 2) + q) ^ (rn & 7)) << 3);
                short8 bh = *(const short8*)(Vh + off);
                short8 bl = *(const short8*)(Vl + off);
#pragma unroll
                for (int mt = 0; mt < 2; ++mt) {
                    acc[mt][nt] = __builtin_amdgcn_mfma_f32_16x16x32_bf16(ah[ks][mt], bh, acc[mt][nt], 0, 0, 0);
                    acc[mt][nt] = __builtin_amdgcn_mfma_f32_16x16x32_bf16(ah[ks][mt], bl, acc[mt][nt], 0, 0, 0);
                    acc[mt][nt] = __builtin_amdgcn_mfma_f32_16x16x32_bf16(al[ks][mt], bh, acc[mt][nt], 0, 0, 0);
                }
            }
        }
    }

    // agree epilogue: acc[mt][nt][reg] = G[i = rb>>3][d = (rb&7)+reg][oe]
#pragma unroll
    for (int mt = 0; mt < 2; ++mt) {
        int rb = m0 + w * 32 + mt * 16 + q * 4;
        int i  = rb >> 3;
        int d0 = rb & 7;                          // 0 or 4 (q parity)
#pragma unroll
        for (int nt = 0; nt < 5; ++nt) {
            int oe = oe0 + nt * 16 + l15;
            float4 wv = *(const float4*)(Wt + (size_t)i * WROW + oe * 8 + d0);
            floatx4 a = acc[mt][nt];
            float p = a[0] * wv.x + a[1] * wv.y + a[2] * wv.z + a[3] * wv.w;
            p += __shfl_xor(p, 1);                 // e-lanes
            p += __shfl_xor(p, 2);
            p += __shfl_xor(p, 4);
            p += __shfl_xor(p, 8);
            p += __shfl_xor(p, 16);                // d-halves (q pairs)
            if ((lane & 31) == 0)
                agree[i * O + nb * 5 + nt] = p;
        }
    }
}

// ---------------------------------------------------------------------------
// MEGA kernel: whole pipeline, software grid barriers between stages.
// 9 barriers replace 8 kernel boundaries.
// ---------------------------------------------------------------------------
__global__ __launch_bounds__(256, 2) void mega_kernel(
    const float* __restrict__ x, const float* __restrict__ W,
    float* __restrict__ out, float* __restrict__ Wt,
    unsigned short* __restrict__ xTh, unsigned short* __restrict__ xTl,
    unsigned short* __restrict__ vhT, unsigned short* __restrict__ vlT,
    float* __restrict__ sp, float* __restrict__ a0, float* __restrict__ a1,
    unsigned* __restrict__ bar)
{
    __shared__ unsigned short Sh[80 * 64], Sl[80 * 64];   // spart & ggemm reuse
    __shared__ float brow_s[16][10];
    __shared__ float cL[16][10];

    unsigned* cnt = bar;
    unsigned* gen = bar + 1;
    int bid = blockIdx.x;
    int t   = threadIdx.x;

    stage_prep(bid, t, x, W, Wt, xTh, xTl);
    gbar(cnt, gen);

    for (int it = 0; it < 3; ++it) {
        stage_spart(bid, t, Sh, Sl, brow_s, cL, x, Wt, a0, a1, sp, it);
        gbar(cnt, gen);
        stage_vred(bid, t, sp, out, vhT, vlT, it == 2);
        if (it == 2) break;
        gbar(cnt, gen);
        stage_ggemm(bid, t, Sh, Sl, xTh, xTl, vhT, vlT, Wt, it == 0 ? a0 : a1);
        gbar(cnt, gen);
    }
}

// ---------------------------------------------------------------------------
extern "C" void kernel_launch(void* const* d_in, const int* in_sizes, int n_in,
                              void* d_out, int out_size, void* d_ws, size_t ws_size,
                              hipStream_t stream)
{
    const float* x = (const float*)d_in[0];   // [256,1152,8]
    const float* W = (const float*)d_in[1];   // [1152,10,8,16]
    float* out = (float*)d_out;               // [256,10,16,1] flat = 40960

    // ws: bar(64B) | a0 | a1 | Wt 5.9MB | sp 11.8MB | xTh/xTl 9.4MB | vhT/vlT
    unsigned* bar = (unsigned*)d_ws;
    float* a0 = (float*)((char*)d_ws + 256);
    float* a1 = a0 + I * O;
    float* Wt = a1 + I * O;
    float* sp = Wt + (size_t)I * OE * DIN;
    unsigned short* xTh = (unsigned short*)(sp + (size_t)PSPLIT * B * OE);
    unsigned short* xTl = xTh + (size_t)XROW * B;
    unsigned short* vhT = xTl + (size_t)XROW * B;
    unsigned short* vlT = vhT + (size_t)B * OE;

    // zero barrier state (memset node is graph-capture legal)
    hipMemsetAsync(d_ws, 0, 64, stream);

    mega_kernel<<<GRID, 256, 0, stream>>>(
        x, W, out, Wt, xTh, xTl, vhT, vlT, sp, a0, a1, bar);
}

// Round 6
// 221.966 us; speedup vs baseline: 5.0836x; 5.0836x over previous
//
#include <hip/hip_runtime.h>
#include <math.h>

#define B    256
#define I    1152
#define O    10
#define DIN  8
#define DOUT 16
#define OE   160          // O*DOUT
#define XROW 9216         // I*DIN (K of the s-GEMM, M of the g-GEMM)
#define WROW 1280         // O*DIN*DOUT (= OE*DIN, Wt row length)
#define PSPLIT 72         // split-K partials
#define CHUNK  16         // i per spart block
#define SI     8          // i per staging round (K-window 64)
#define GRID   288        // 4*PSPLIT blocks; co-resident (<=2 blk/CU bound)

#define WPREP_JOBS 720    // I*OE/256

typedef __attribute__((ext_vector_type(8))) short short8;
typedef __attribute__((ext_vector_type(4))) float floatx4;

__device__ __forceinline__ unsigned short f2bf(float f) {
    unsigned u = __builtin_bit_cast(unsigned, f);
    u += 0x7fffu + ((u >> 16) & 1u);          // RNE
    return (unsigned short)(u >> 16);
}
__device__ __forceinline__ float bf2f(unsigned short h) {
    unsigned u = ((unsigned)h) << 16;
    return __builtin_bit_cast(float, u);
}

// ---------------------------------------------------------------------------
// Software grid barrier, FIXED (R5 post-mortem):
//  - fences issued ONCE per block by thread 0 (cache-wide wbl2/inv are
//    per-cache ops; 256 threads each fencing was ~20k L2 flushes/kernel)
//  - spin uses RELAXED atomic load (sc1: bypasses XCD L2, NO buffer_inv
//    per poll -- the ACQUIRE-in-loop was invalidating L2 every iteration)
//  - one ACQUIRE fence after the generation flips.
// __syncthreads() before thread-0's release fence guarantees vmcnt(0)
// (compiler drains stores to L2 before s_barrier), so the single wbl2
// flushes everything this block wrote.
// ---------------------------------------------------------------------------
__device__ __forceinline__ void gbar(unsigned* cnt, unsigned* gen)
{
    __syncthreads();
    if (threadIdx.x == 0) {
        __builtin_amdgcn_fence(__ATOMIC_RELEASE, "agent");   // one wbl2
        unsigned g = __hip_atomic_load(gen, __ATOMIC_RELAXED, __HIP_MEMORY_SCOPE_AGENT);
        unsigned a = __hip_atomic_fetch_add(cnt, 1u, __ATOMIC_RELAXED, __HIP_MEMORY_SCOPE_AGENT);
        if (a == GRID - 1u) {
            __hip_atomic_store(cnt, 0u, __ATOMIC_RELAXED, __HIP_MEMORY_SCOPE_AGENT);
            __hip_atomic_store(gen, g + 1u, __ATOMIC_RELAXED, __HIP_MEMORY_SCOPE_AGENT);
        } else {
            unsigned spins = 0;
            while (__hip_atomic_load(gen, __ATOMIC_RELAXED, __HIP_MEMORY_SCOPE_AGENT) == g) {
                __builtin_amdgcn_s_sleep(8);
                if (++spins > (1u << 20)) break;             // failsafe, ~0.2 s
            }
        }
        __builtin_amdgcn_fence(__ATOMIC_ACQUIRE, "agent");   // one inv
    }
    __syncthreads();
}

// ---------------------------------------------------------------------------
// STAGE: prep (one-time). W -> Wt[i][oe][d] fp32 (d-contiguous);
// x -> xTh/xTl[(i*8+d)][b] bf16 hi/lo (g-GEMM A operand);
// x -> xh/xl[b][k] bf16 hi/lo (spart A operand, k-contiguous).
// ---------------------------------------------------------------------------
__device__ __forceinline__ void stage_prep(
    int bid, int t,
    const float* __restrict__ x, const float* __restrict__ W,
    float* __restrict__ Wt,
    unsigned short* __restrict__ xTh, unsigned short* __restrict__ xTl,
    unsigned short* __restrict__ xh,  unsigned short* __restrict__ xl)
{
#pragma unroll
    for (int r = 0; r < 3; ++r) {
        int job = bid + GRID * r;
        if (job < WPREP_JOBS) {
            int g  = job * 256 + t;               // (i, oe) pair
            int i  = g / OE;
            int oe = g - i * OE;
            int o  = oe >> 4;
            int e  = oe & 15;
            const float* wp = W + (size_t)i * WROW + o * (DIN * DOUT) + e;
            float4 a, b;
            a.x = wp[0 * DOUT]; a.y = wp[1 * DOUT]; a.z = wp[2 * DOUT]; a.w = wp[3 * DOUT];
            b.x = wp[4 * DOUT]; b.y = wp[5 * DOUT]; b.z = wp[6 * DOUT]; b.w = wp[7 * DOUT];
            float4* dst = (float4*)(Wt + (size_t)g * 8);
            dst[0] = a;
            dst[1] = b;
        }
    }
#pragma unroll
    for (int r = 0; r < 4; ++r) {                 // 4*288 = 1152 jobs exactly
        int g2  = bid + GRID * r;
        int idb = g2 % 144;
        int bb  = g2 / 144;
        int id  = idb * 64 + (t & 63);            // (i,d) flat row
        int b0  = bb * 32 + (t >> 6) * 8;         // 8 batch elems per thread
        float v[8];
#pragma unroll
        for (int j = 0; j < 8; ++j)
            v[j] = x[(size_t)(b0 + j) * XROW + id];
        short8 h8, l8;
#pragma unroll
        for (int j = 0; j < 8; ++j) {
            unsigned short h = f2bf(v[j]);
            h8[j] = (short)h;
            l8[j] = (short)f2bf(v[j] - bf2f(h));
        }
        *(short8*)(xTh + (size_t)id * B + b0) = h8;
        *(short8*)(xTl + (size_t)id * B + b0) = l8;
    }
#pragma unroll
    for (int r = 0; r < 8; ++r) {                 // 8*288*256 = 589824 float4 jobs
        int g = (bid + GRID * r) * 256 + t;
        float4 v = ((const float4*)x)[g];
        ushort4 h, l;
        h.x = f2bf(v.x); l.x = f2bf(v.x - bf2f(h.x));
        h.y = f2bf(v.y); l.y = f2bf(v.y - bf2f(h.y));
        h.z = f2bf(v.z); l.z = f2bf(v.z - bf2f(h.z));
        h.w = f2bf(v.w); l.w = f2bf(v.w - bf2f(h.w));
        ((ushort4*)xh)[g] = h;
        ((ushort4*)xl)[g] = l;
    }
}

// ---------------------------------------------------------------------------
// STAGE: spart. MFMA bf16 hi/lo split-K GEMM + routing prologue.
// it==0: c = 0.1. it>=1: b = (a0 [+ a1])/B, softmax -> cL in LDS.
// s[b,oe] = sum_k x[b,k]*(c[i,o]*W)[k,oe]; 3 MFMAs/tile (xl*wl dropped).
// A-fragments now load pre-split bf16 from xh/xl (16 B, no VALU split).
// ---------------------------------------------------------------------------
__device__ __forceinline__ void stage_spart(
    int bid, int t,
    unsigned short* __restrict__ Wh, unsigned short* __restrict__ Wl,
    float (*brow_s)[10], float (*cL)[10],
    const unsigned short* __restrict__ xh, const unsigned short* __restrict__ xl,
    const float* __restrict__ Wt,
    const float* __restrict__ a0, const float* __restrict__ a1,
    float* __restrict__ sp, int it)
{
    int ic  = bid >> 2;
    int mb  = (bid >> 1) & 1;
    int nb  = bid & 1;
    int b0  = mb * 128;
    int oe0 = nb * 80;
    int i0  = ic * CHUNK;

    int w    = t >> 6;
    int lane = t & 63;
    int l15  = lane & 15;
    int q    = lane >> 4;

    // routing prologue: logits from agree partials, softmax -> cL
    if (it) {
        if (t < 160) {
            int iL = t / 10;
            int o  = t - iL * 10;
            int i  = i0 + iL;
            float bo = a0[i * O + o] * (1.f / (float)B);
            if (it == 2) bo += a1[i * O + o] * (1.f / (float)B);
            brow_s[iL][o] = bo;
        }
        __syncthreads();
        if (t < 16) {
            float m = brow_s[t][0];
#pragma unroll
            for (int o = 1; o < O; ++o) m = fmaxf(m, brow_s[t][o]);
            float ex[O];
            float sum = 0.f;
#pragma unroll
            for (int o = 0; o < O; ++o) { ex[o] = __expf(brow_s[t][o] - m); sum += ex[o]; }
            float inv = 1.f / sum;
#pragma unroll
            for (int o = 0; o < O; ++o) cL[t][o] = ex[o] * inv;
        }
        __syncthreads();
    }

    floatx4 acc[2][5];
#pragma unroll
    for (int mt = 0; mt < 2; ++mt)
#pragma unroll
        for (int nt = 0; nt < 5; ++nt) acc[mt][nt] = (floatx4)(0.f);

#pragma unroll
    for (int round = 0; round < CHUNK / SI; ++round) {
        int si0 = i0 + round * SI;
        if (round) __syncthreads();

        // X fragments: direct bf16 hi/lo loads (16 B each, coalesced)
        short8 ah[2][2], al[2][2];                // [ks][mt]
#pragma unroll
        for (int ks = 0; ks < 2; ++ks)
#pragma unroll
            for (int mt = 0; mt < 2; ++mt) {
                size_t goff = (size_t)(b0 + w * 32 + mt * 16 + l15) * XROW
                            + (size_t)si0 * 8 + (ks << 5) + (q << 3);
                ah[ks][mt] = *(const short8*)(xh + goff);
                al[ks][mt] = *(const short8*)(xl + goff);
            }

        // stage W: coalesced loads from Wt, scale by c, split hi/lo
#pragma unroll
        for (int r = 0; r < 3; ++r) {
            int p = t + 256 * r;                  // (oe-local, i-local) pair
            if (p < 640) {
                int oeL = p % 80;
                int iL  = p / 80;                 // 0..7
                int o   = (oe0 + oeL) >> 4;
                const float* wp = Wt + ((size_t)(si0 + iL) * OE + oe0 + oeL) * 8;
                float cv = it ? cL[round * SI + iL][o] : 0.1f;
                float4 w0 = *(const float4*)wp;
                float4 w1 = *(const float4*)(wp + 4);
                float wv[8] = {w0.x, w0.y, w0.z, w0.w, w1.x, w1.y, w1.z, w1.w};
                short8 hv, lv;
#pragma unroll
                for (int d = 0; d < 8; ++d) {
                    float s = wv[d] * cv;
                    unsigned short h = f2bf(s);
                    hv[d] = (short)h;
                    lv[d] = (short)f2bf(s - bf2f(h));
                }
                int off = oeL * 64 + ((iL ^ (oeL & 7)) << 3);
                *(short8*)(Wh + off) = hv;
                *(short8*)(Wl + off) = lv;
            }
        }
        __syncthreads();

        // 2 K-steps of 32 over the staged window
#pragma unroll
        for (int ks = 0; ks < 2; ++ks) {
#pragma unroll
            for (int nt = 0; nt < 5; ++nt) {
                int rn  = nt * 16 + l15;
                int off = rn * 64 + ((((ks << 2) + q) ^ (rn & 7)) << 3);
                short8 bh = *(const short8*)(Wh + off);
                short8 bl = *(const short8*)(Wl + off);
#pragma unroll
                for (int mt = 0; mt < 2; ++mt) {
                    acc[mt][nt] = __builtin_amdgcn_mfma_f32_16x16x32_bf16(ah[ks][mt], bh, acc[mt][nt], 0, 0, 0);
                    acc[mt][nt] = __builtin_amdgcn_mfma_f32_16x16x32_bf16(ah[ks][mt], bl, acc[mt][nt], 0, 0, 0);
                    acc[mt][nt] = __builtin_amdgcn_mfma_f32_16x16x32_bf16(al[ks][mt], bh, acc[mt][nt], 0, 0, 0);
                }
            }
        }
    }

    // epilogue: C/D layout col=lane&15, row=(lane>>4)*4+reg (m89/m91)
    float* base = sp + (size_t)ic * (B * OE);
#pragma unroll
    for (int mt = 0; mt < 2; ++mt) {
        int row0 = b0 + w * 32 + mt * 16 + q * 4;
#pragma unroll
        for (int nt = 0; nt < 5; ++nt) {
            int col = oe0 + nt * 16 + l15;
#pragma unroll
            for (int reg = 0; reg < 4; ++reg)
                base[(row0 + reg) * OE + col] = acc[mt][nt][reg];
        }
    }
}

// ---------------------------------------------------------------------------
// STAGE: vred. Sum PSPLIT partials + squash; iters 0,1 -> v bf16 hi/lo
// transposed [oe][b]; iter 2 -> final out. 160 of 288 blocks active.
// ---------------------------------------------------------------------------
__device__ __forceinline__ void stage_vred(
    int bid, int t, const float* __restrict__ sp, float* __restrict__ out,
    unsigned short* __restrict__ vhT, unsigned short* __restrict__ vlT, int last)
{
    if (bid >= 160) return;
    int g = bid * 256 + t;                      // [b][o][e] flat
    float s = 0.f;
#pragma unroll 8
    for (int ic = 0; ic < PSPLIT; ++ic) s += sp[(size_t)ic * (B * OE) + g];

    float ss = s * s;
    ss += __shfl_xor(ss, 1, 16);
    ss += __shfl_xor(ss, 2, 16);
    ss += __shfl_xor(ss, 4, 16);
    ss += __shfl_xor(ss, 8, 16);
    float f = sqrtf(ss) / (1.f + ss);           // squash factor
    float val = s * f;

    if (last) {
        out[g] = val;
    } else {
        int b  = g / OE;
        int oe = g - b * OE;
        unsigned short h = f2bf(val);
        vhT[oe * B + b] = h;
        vlT[oe * B + b] = f2bf(val - bf2f(h));
    }
}

// ---------------------------------------------------------------------------
// STAGE: ggemm + in-wave agree epilogue. G[(i,d)][oe] = sum_b xT*v via MFMA;
// G never materialized: agree[i,o] = sum_{d,e} Wt*G via float4-dot + shfl
// tree. 144 of 288 blocks active. Writes raw dot (1/B applied in prologue).
// ---------------------------------------------------------------------------
__device__ __forceinline__ void stage_ggemm(
    int bid, int t,
    unsigned short* __restrict__ Vh, unsigned short* __restrict__ Vl,
    const unsigned short* __restrict__ xTh, const unsigned short* __restrict__ xTl,
    const unsigned short* __restrict__ vhT, const unsigned short* __restrict__ vlT,
    const float* __restrict__ Wt, float* __restrict__ agree)
{
    if (bid >= 144) return;
    int m0  = (bid >> 1) * 128;
    int nb  = bid & 1;
    int oe0 = nb * 80;

    int w    = t >> 6;
    int lane = t & 63;
    int l15  = lane & 15;
    int q    = lane >> 4;

    floatx4 acc[2][5];
#pragma unroll
    for (int mt = 0; mt < 2; ++mt)
#pragma unroll
        for (int nt = 0; nt < 5; ++nt) acc[mt][nt] = (floatx4)(0.f);

#pragma unroll
    for (int win = 0; win < 4; ++win) {
        int k0 = win * 64;
        if (win) __syncthreads();

        // stage V window [80 oe][64 b], XOR-swizzled 16B chunks
#pragma unroll
        for (int r = 0; r < 3; ++r) {
            int p = t + 256 * r;
            if (p < 640) {
                int row = p >> 3;
                int ch  = p & 7;
                int off = row * 64 + ((ch ^ (row & 7)) << 3);
                size_t gsrc = (size_t)(oe0 + row) * B + k0 + (ch << 3);
                *(short8*)(Vh + off) = *(const short8*)(vhT + gsrc);
                *(short8*)(Vl + off) = *(const short8*)(vlT + gsrc);
            }
        }
        __syncthreads();

        // A fragments direct from xT (b-contiguous rows)
        short8 ah[2][2], al[2][2];
#pragma unroll
        for (int ks = 0; ks < 2; ++ks)
#pragma unroll
            for (int mt = 0; mt < 2; ++mt) {
                size_t ga = (size_t)(m0 + w * 32 + mt * 16 + l15) * B
                          + k0 + (ks << 5) + (q << 3);
                ah[ks][mt] = *(const short8*)(xTh + ga);
                al[ks][mt] = *(const short8*)(xTl + ga);
            }

#pragma unroll
        for (int ks = 0; ks < 2; ++ks) {
#pragma unroll
            for (int nt = 0; nt < 5; ++nt) {
                int rn  = nt * 16 + l15;
                int off = rn * 64 + ((((ks << 2) + q) ^ (rn & 7)) << 3);
                short8 bh = *(const short8*)(Vh + off);
                short8 bl = *(const short8*)(Vl + off);
#pragma unroll
                for (int mt = 0; mt < 2; ++mt) {
                    acc[mt][nt] = __builtin_amdgcn_mfma_f32_16x16x32_bf16(ah[ks][mt], bh, acc[mt][nt], 0, 0, 0);
                    acc[mt][nt] = __builtin_amdgcn_mfma_f32_16x16x32_bf16(ah[ks][mt], bl, acc[mt][nt], 0, 0, 0);
                    acc[mt][nt] = __builtin_amdgcn_mfma_f32_16x16x32_bf16(al[ks][mt], bh, acc[mt][nt], 0, 0, 0);
                }
            }
        }
    }

    // agree epilogue: acc[mt][nt][reg] = G[i = rb>>3][d = (rb&7)+reg][oe]
#pragma unroll
    for (int mt = 0; mt < 2; ++mt) {
        int rb = m0 + w * 32 + mt * 16 + q * 4;
        int i  = rb >> 3;
        int d0 = rb & 7;                          // 0 or 4 (q parity)
#pragma unroll
        for (int nt = 0; nt < 5; ++nt) {
            int oe = oe0 + nt * 16 + l15;
            float4 wv = *(const float4*)(Wt + (size_t)i * WROW + oe * 8 + d0);
            floatx4 a = acc[mt][nt];
            float p = a[0] * wv.x + a[1] * wv.y + a[2] * wv.z + a[3] * wv.w;
            p += __shfl_xor(p, 1);                 // e-lanes
            p += __shfl_xor(p, 2);
            p += __shfl_xor(p, 4);
            p += __shfl_xor(p, 8);
            p += __shfl_xor(p, 16);                // d-halves (q pairs)
            if ((lane & 31) == 0)
                agree[i * O + nb * 5 + nt] = p;
        }
    }
}

// ---------------------------------------------------------------------------
// MEGA kernel: whole pipeline, software grid barriers between stages.
// ---------------------------------------------------------------------------
__global__ __launch_bounds__(256, 2) void mega_kernel(
    const float* __restrict__ x, const float* __restrict__ W,
    float* __restrict__ out, float* __restrict__ Wt,
    unsigned short* __restrict__ xTh, unsigned short* __restrict__ xTl,
    unsigned short* __restrict__ xh,  unsigned short* __restrict__ xl,
    unsigned short* __restrict__ vhT, unsigned short* __restrict__ vlT,
    float* __restrict__ sp, float* __restrict__ a0, float* __restrict__ a1,
    unsigned* __restrict__ bar)
{
    __shared__ unsigned short Sh[80 * 64], Sl[80 * 64];   // spart & ggemm reuse
    __shared__ float brow_s[16][10];
    __shared__ float cL[16][10];

    unsigned* cnt = bar;            // cacheline 0
    unsigned* gen = bar + 32;       // cacheline 1 (decouple poll from RMW)
    int bid = blockIdx.x;
    int t   = threadIdx.x;

    stage_prep(bid, t, x, W, Wt, xTh, xTl, xh, xl);
    gbar(cnt, gen);

    for (int it = 0; it < 3; ++it) {
        stage_spart(bid, t, Sh, Sl, brow_s, cL, xh, xl, Wt, a0, a1, sp, it);
        gbar(cnt, gen);
        stage_vred(bid, t, sp, out, vhT, vlT, it == 2);
        if (it == 2) break;
        gbar(cnt, gen);
        stage_ggemm(bid, t, Sh, Sl, xTh, xTl, vhT, vlT, Wt, it == 0 ? a0 : a1);
        gbar(cnt, gen);
    }
}

// ---------------------------------------------------------------------------
extern "C" void kernel_launch(void* const* d_in, const int* in_sizes, int n_in,
                              void* d_out, int out_size, void* d_ws, size_t ws_size,
                              hipStream_t stream)
{
    const float* x = (const float*)d_in[0];   // [256,1152,8]
    const float* W = (const float*)d_in[1];   // [1152,10,8,16]
    float* out = (float*)d_out;               // [256,10,16,1] flat = 40960

    // ws: bar 256B | a0 | a1 | Wt 5.9MB | sp 11.8MB | xTh/xTl 9.4MB |
    //     xh/xl 9.4MB | vhT/vlT           (~37 MB of 256 MB)
    unsigned* bar = (unsigned*)d_ws;
    float* a0 = (float*)((char*)d_ws + 256);
    float* a1 = a0 + I * O;
    float* Wt = a1 + I * O;
    float* sp = Wt + (size_t)I * OE * DIN;
    unsigned short* xTh = (unsigned short*)(sp + (size_t)PSPLIT * B * OE);
    unsigned short* xTl = xTh + (size_t)XROW * B;
    unsigned short* xh  = xTl + (size_t)XROW * B;
    unsigned short* xl  = xh  + (size_t)XROW * B;
    unsigned short* vhT = xl  + (size_t)XROW * B;
    unsigned short* vlT = vhT + (size_t)B * OE;

    // zero barrier state (memset node is graph-capture legal)
    hipMemsetAsync(d_ws, 0, 256, stream);

    mega_kernel<<<GRID, 256, 0, stream>>>(
        x, W, out, Wt, xTh, xTl, xh, xl, vhT, vlT, sp, a0, a1, bar);
}

// Round 7
// 176.094 us; speedup vs baseline: 6.4079x; 1.2605x over previous
//
#include <hip/hip_runtime.h>
#include <math.h>

#define B    256
#define I    1152
#define O    10
#define DIN  8
#define DOUT 16
#define OE   160          // O*DOUT
#define XROW 9216         // I*DIN (K of the s-GEMM, M of the g-GEMM)
#define WROW 1280         // O*DIN*DOUT (= OE*DIN, Wt row length)
#define PSPLIT 72         // split-K partials
#define CHUNK  16         // i per spart block
#define SI     8          // i per staging round (K-window 64)
#define GRID   288        // 4*PSPLIT blocks; co-resident (124 VGPR -> 4 blk/CU cap)

#define WPREP_JOBS 720    // I*OE/256

typedef __attribute__((ext_vector_type(8))) short short8;
typedef __attribute__((ext_vector_type(4))) float floatx4;

// sc1 accessors: bypass per-XCD L2, served by the shared memory-side L3.
// All iteration-crossing data (sp, vT, a0/a1) goes through these, so the
// steady-state grid barrier needs NO cache-wide fences.
#define AL(p)    __hip_atomic_load((p),      __ATOMIC_RELAXED, __HIP_MEMORY_SCOPE_AGENT)
#define AS(p, v) __hip_atomic_store((p), (v), __ATOMIC_RELAXED, __HIP_MEMORY_SCOPE_AGENT)

__device__ __forceinline__ unsigned short f2bf(float f) {
    unsigned u = __builtin_bit_cast(unsigned, f);
    u += 0x7fffu + ((u >> 16) & 1u);          // RNE
    return (unsigned short)(u >> 16);
}
__device__ __forceinline__ float bf2f(unsigned short h) {
    unsigned u = ((unsigned)h) << 16;
    return __builtin_bit_cast(float, u);
}

// ---------------------------------------------------------------------------
// FULL barrier (one-time, after prep): agent release/acquire fences flush
// the plain-stored prep outputs (Wt, xT, xh/xl) across XCDs.
// ---------------------------------------------------------------------------
__device__ __forceinline__ void gbar_full(unsigned* cnt, unsigned* gen)
{
    __syncthreads();
    if (threadIdx.x == 0) {
        __builtin_amdgcn_fence(__ATOMIC_RELEASE, "agent");   // wbl2
        unsigned g = __hip_atomic_load(gen, __ATOMIC_RELAXED, __HIP_MEMORY_SCOPE_AGENT);
        unsigned a = __hip_atomic_fetch_add(cnt, 1u, __ATOMIC_RELAXED, __HIP_MEMORY_SCOPE_AGENT);
        if (a == GRID - 1u) {
            __hip_atomic_store(cnt, 0u, __ATOMIC_RELAXED, __HIP_MEMORY_SCOPE_AGENT);
            __hip_atomic_store(gen, g + 1u, __ATOMIC_RELAXED, __HIP_MEMORY_SCOPE_AGENT);
        } else {
            unsigned spins = 0;
            while (__hip_atomic_load(gen, __ATOMIC_RELAXED, __HIP_MEMORY_SCOPE_AGENT) == g) {
                __builtin_amdgcn_s_sleep(4);
                if (++spins > (1u << 20)) break;             // failsafe
            }
        }
        __builtin_amdgcn_fence(__ATOMIC_ACQUIRE, "agent");   // inv
    }
    __syncthreads();
}

// ---------------------------------------------------------------------------
// LIGHT barrier (steady state): NO cache-wide fences. Correctness argument:
//  - writer side: __syncthreads() emits s_waitcnt vmcnt(0) per wave, so all
//    sc1 stores have reached the L3 coherence point before thread 0 runs;
//  - gen flip uses a RELEASE store (orders the cnt reset; <=1 wbl2/barrier
//    from the single last-arriving block, and wbl2 does not invalidate
//    clean read-only lines);
//  - reader side: all cross-stage reads are sc1 loads (L2-bypass), so no
//    stale-line hazard; read-only data (Wt, xh/xl, xT) stays L2-warm.
// ---------------------------------------------------------------------------
__device__ __forceinline__ void gbar_light(unsigned* cnt, unsigned* gen)
{
    __syncthreads();
    if (threadIdx.x == 0) {
        unsigned g = __hip_atomic_load(gen, __ATOMIC_RELAXED, __HIP_MEMORY_SCOPE_AGENT);
        unsigned a = __hip_atomic_fetch_add(cnt, 1u, __ATOMIC_RELAXED, __HIP_MEMORY_SCOPE_AGENT);
        if (a == GRID - 1u) {
            __hip_atomic_store(cnt, 0u, __ATOMIC_RELAXED, __HIP_MEMORY_SCOPE_AGENT);
            __hip_atomic_store(gen, g + 1u, __ATOMIC_RELEASE, __HIP_MEMORY_SCOPE_AGENT);
        } else {
            unsigned spins = 0;
            while (__hip_atomic_load(gen, __ATOMIC_RELAXED, __HIP_MEMORY_SCOPE_AGENT) == g) {
                __builtin_amdgcn_s_sleep(4);
                if (++spins > (1u << 20)) break;             // failsafe
            }
        }
    }
    __syncthreads();
}

// ---------------------------------------------------------------------------
// STAGE: prep (one-time). W -> Wt[i][oe][d] fp32; x -> xTh/xTl[(i,d)][b]
// bf16 hi/lo (g-GEMM A); x -> xh/xl[b][k] bf16 hi/lo (spart A).
// ---------------------------------------------------------------------------
__device__ __forceinline__ void stage_prep(
    int bid, int t,
    const float* __restrict__ x, const float* __restrict__ W,
    float* __restrict__ Wt,
    unsigned short* __restrict__ xTh, unsigned short* __restrict__ xTl,
    unsigned short* __restrict__ xh,  unsigned short* __restrict__ xl)
{
#pragma unroll
    for (int r = 0; r < 3; ++r) {
        int job = bid + GRID * r;
        if (job < WPREP_JOBS) {
            int g  = job * 256 + t;               // (i, oe) pair
            int i  = g / OE;
            int oe = g - i * OE;
            int o  = oe >> 4;
            int e  = oe & 15;
            const float* wp = W + (size_t)i * WROW + o * (DIN * DOUT) + e;
            float4 a, b;
            a.x = wp[0 * DOUT]; a.y = wp[1 * DOUT]; a.z = wp[2 * DOUT]; a.w = wp[3 * DOUT];
            b.x = wp[4 * DOUT]; b.y = wp[5 * DOUT]; b.z = wp[6 * DOUT]; b.w = wp[7 * DOUT];
            float4* dst = (float4*)(Wt + (size_t)g * 8);
            dst[0] = a;
            dst[1] = b;
        }
    }
#pragma unroll
    for (int r = 0; r < 4; ++r) {                 // 4*288 = 1152 jobs exactly
        int g2  = bid + GRID * r;
        int idb = g2 % 144;
        int bb  = g2 / 144;
        int id  = idb * 64 + (t & 63);            // (i,d) flat row
        int b0  = bb * 32 + (t >> 6) * 8;         // 8 batch elems per thread
        float v[8];
#pragma unroll
        for (int j = 0; j < 8; ++j)
            v[j] = x[(size_t)(b0 + j) * XROW + id];
        short8 h8, l8;
#pragma unroll
        for (int j = 0; j < 8; ++j) {
            unsigned short h = f2bf(v[j]);
            h8[j] = (short)h;
            l8[j] = (short)f2bf(v[j] - bf2f(h));
        }
        *(short8*)(xTh + (size_t)id * B + b0) = h8;
        *(short8*)(xTl + (size_t)id * B + b0) = l8;
    }
#pragma unroll
    for (int r = 0; r < 8; ++r) {                 // 8*288*256 float4 jobs
        int g = (bid + GRID * r) * 256 + t;
        float4 v = ((const float4*)x)[g];
        ushort4 h, l;
        h.x = f2bf(v.x); l.x = f2bf(v.x - bf2f(h.x));
        h.y = f2bf(v.y); l.y = f2bf(v.y - bf2f(h.y));
        h.z = f2bf(v.z); l.z = f2bf(v.z - bf2f(h.z));
        h.w = f2bf(v.w); l.w = f2bf(v.w - bf2f(h.w));
        ((ushort4*)xh)[g] = h;
        ((ushort4*)xl)[g] = l;
    }
}

// ---------------------------------------------------------------------------
// STAGE: spart. MFMA bf16 hi/lo split-K GEMM + routing prologue.
// it==0: c=0.1. it>=1: b=(a0[+a1])/B (sc1 loads), softmax -> cL.
// sp partial writes are sc1 stores.
// ---------------------------------------------------------------------------
__device__ __forceinline__ void stage_spart(
    int bid, int t,
    unsigned short* __restrict__ Wh, unsigned short* __restrict__ Wl,
    float (*brow_s)[10], float (*cL)[10],
    const unsigned short* __restrict__ xh, const unsigned short* __restrict__ xl,
    const float* __restrict__ Wt,
    const float* __restrict__ a0, const float* __restrict__ a1,
    float* __restrict__ sp, int it)
{
    int ic  = bid >> 2;
    int mb  = (bid >> 1) & 1;
    int nb  = bid & 1;
    int b0  = mb * 128;
    int oe0 = nb * 80;
    int i0  = ic * CHUNK;

    int w    = t >> 6;
    int lane = t & 63;
    int l15  = lane & 15;
    int q    = lane >> 4;

    if (it) {
        if (t < 160) {
            int iL = t / 10;
            int o  = t - iL * 10;
            int i  = i0 + iL;
            float bo = AL(&a0[i * O + o]) * (1.f / (float)B);
            if (it == 2) bo += AL(&a1[i * O + o]) * (1.f / (float)B);
            brow_s[iL][o] = bo;
        }
        __syncthreads();
        if (t < 16) {
            float m = brow_s[t][0];
#pragma unroll
            for (int o = 1; o < O; ++o) m = fmaxf(m, brow_s[t][o]);
            float ex[O];
            float sum = 0.f;
#pragma unroll
            for (int o = 0; o < O; ++o) { ex[o] = __expf(brow_s[t][o] - m); sum += ex[o]; }
            float inv = 1.f / sum;
#pragma unroll
            for (int o = 0; o < O; ++o) cL[t][o] = ex[o] * inv;
        }
        __syncthreads();
    }

    floatx4 acc[2][5];
#pragma unroll
    for (int mt = 0; mt < 2; ++mt)
#pragma unroll
        for (int nt = 0; nt < 5; ++nt) acc[mt][nt] = (floatx4)(0.f);

#pragma unroll
    for (int round = 0; round < CHUNK / SI; ++round) {
        int si0 = i0 + round * SI;
        if (round) __syncthreads();

        // X fragments: direct bf16 hi/lo loads (read-only, L2-cached)
        short8 ah[2][2], al[2][2];                // [ks][mt]
#pragma unroll
        for (int ks = 0; ks < 2; ++ks)
#pragma unroll
            for (int mt = 0; mt < 2; ++mt) {
                size_t goff = (size_t)(b0 + w * 32 + mt * 16 + l15) * XROW
                            + (size_t)si0 * 8 + (ks << 5) + (q << 3);
                ah[ks][mt] = *(const short8*)(xh + goff);
                al[ks][mt] = *(const short8*)(xl + goff);
            }

        // stage W: coalesced loads from Wt, scale by c, split hi/lo
#pragma unroll
        for (int r = 0; r < 3; ++r) {
            int p = t + 256 * r;                  // (oe-local, i-local) pair
            if (p < 640) {
                int oeL = p % 80;
                int iL  = p / 80;                 // 0..7
                int o   = (oe0 + oeL) >> 4;
                const float* wp = Wt + ((size_t)(si0 + iL) * OE + oe0 + oeL) * 8;
                float cv = it ? cL[round * SI + iL][o] : 0.1f;
                float4 w0 = *(const float4*)wp;
                float4 w1 = *(const float4*)(wp + 4);
                float wv[8] = {w0.x, w0.y, w0.z, w0.w, w1.x, w1.y, w1.z, w1.w};
                short8 hv, lv;
#pragma unroll
                for (int d = 0; d < 8; ++d) {
                    float s = wv[d] * cv;
                    unsigned short h = f2bf(s);
                    hv[d] = (short)h;
                    lv[d] = (short)f2bf(s - bf2f(h));
                }
                int off = oeL * 64 + ((iL ^ (oeL & 7)) << 3);
                *(short8*)(Wh + off) = hv;
                *(short8*)(Wl + off) = lv;
            }
        }
        __syncthreads();

        // 2 K-steps of 32 over the staged window
#pragma unroll
        for (int ks = 0; ks < 2; ++ks) {
#pragma unroll
            for (int nt = 0; nt < 5; ++nt) {
                int rn  = nt * 16 + l15;
                int off = rn * 64 + ((((ks << 2) + q) ^ (rn & 7)) << 3);
                short8 bh = *(const short8*)(Wh + off);
                short8 bl = *(const short8*)(Wl + off);
#pragma unroll
                for (int mt = 0; mt < 2; ++mt) {
                    acc[mt][nt] = __builtin_amdgcn_mfma_f32_16x16x32_bf16(ah[ks][mt], bh, acc[mt][nt], 0, 0, 0);
                    acc[mt][nt] = __builtin_amdgcn_mfma_f32_16x16x32_bf16(ah[ks][mt], bl, acc[mt][nt], 0, 0, 0);
                    acc[mt][nt] = __builtin_amdgcn_mfma_f32_16x16x32_bf16(al[ks][mt], bh, acc[mt][nt], 0, 0, 0);
                }
            }
        }
    }

    // epilogue: sc1 stores of the partial tile
    float* base = sp + (size_t)ic * (B * OE);
#pragma unroll
    for (int mt = 0; mt < 2; ++mt) {
        int row0 = b0 + w * 32 + mt * 16 + q * 4;
#pragma unroll
        for (int nt = 0; nt < 5; ++nt) {
            int col = oe0 + nt * 16 + l15;
#pragma unroll
            for (int reg = 0; reg < 4; ++reg)
                AS(&base[(row0 + reg) * OE + col], acc[mt][nt][reg]);
        }
    }
}

// ---------------------------------------------------------------------------
// STAGE: vred. Sum PSPLIT partials (sc1 loads) + squash; iters 0,1 -> packed
// v bf16 hi|lo as one uint [oe][b] (sc1 store); iter 2 -> final out (plain).
// ---------------------------------------------------------------------------
__device__ __forceinline__ void stage_vred(
    int bid, int t, const float* __restrict__ sp, float* __restrict__ out,
    unsigned* __restrict__ vT, int last)
{
    if (bid >= 160) return;
    int g = bid * 256 + t;                      // [b][o][e] flat
    float s = 0.f;
#pragma unroll 8
    for (int ic = 0; ic < PSPLIT; ++ic) s += AL(&sp[(size_t)ic * (B * OE) + g]);

    float ss = s * s;
    ss += __shfl_xor(ss, 1, 16);
    ss += __shfl_xor(ss, 2, 16);
    ss += __shfl_xor(ss, 4, 16);
    ss += __shfl_xor(ss, 8, 16);
    float f = sqrtf(ss) / (1.f + ss);           // squash factor
    float val = s * f;

    if (last) {
        out[g] = val;
    } else {
        int b  = g / OE;
        int oe = g - b * OE;
        unsigned short h = f2bf(val);
        unsigned pack = (unsigned)h | ((unsigned)f2bf(val - bf2f(h)) << 16);
        AS(&vT[oe * B + b], pack);
    }
}

// ---------------------------------------------------------------------------
// STAGE: ggemm + in-wave agree epilogue. G[(i,d)][oe] = sum_b xT*v via MFMA;
// v staged from packed vT via 64-bit sc1 loads + in-register unpack.
// agree writes are sc1 stores. 144 of 288 blocks active.
// ---------------------------------------------------------------------------
__device__ __forceinline__ void stage_ggemm(
    int bid, int t,
    unsigned short* __restrict__ Vh, unsigned short* __restrict__ Vl,
    const unsigned short* __restrict__ xTh, const unsigned short* __restrict__ xTl,
    const unsigned* __restrict__ vT,
    const float* __restrict__ Wt, float* __restrict__ agree)
{
    if (bid >= 144) return;
    int m0  = (bid >> 1) * 128;
    int nb  = bid & 1;
    int oe0 = nb * 80;

    int w    = t >> 6;
    int lane = t & 63;
    int l15  = lane & 15;
    int q    = lane >> 4;

    floatx4 acc[2][5];
#pragma unroll
    for (int mt = 0; mt < 2; ++mt)
#pragma unroll
        for (int nt = 0; nt < 5; ++nt) acc[mt][nt] = (floatx4)(0.f);

#pragma unroll
    for (int win = 0; win < 4; ++win) {
        int k0 = win * 64;
        if (win) __syncthreads();

        // stage V window [80 oe][64 b] from packed vT, XOR-swizzled
#pragma unroll
        for (int r = 0; r < 3; ++r) {
            int p = t + 256 * r;
            if (p < 640) {
                int row = p >> 3;
                int ch  = p & 7;
                const unsigned long long* vp =
                    (const unsigned long long*)(vT + (size_t)(oe0 + row) * B + k0 + (ch << 3));
                short8 hv, lv;
#pragma unroll
                for (int j = 0; j < 4; ++j) {
                    unsigned long long u = AL(&vp[j]);
                    unsigned lo = (unsigned)u, hi = (unsigned)(u >> 32);
                    hv[2 * j]     = (short)(lo & 0xffffu);
                    lv[2 * j]     = (short)(lo >> 16);
                    hv[2 * j + 1] = (short)(hi & 0xffffu);
                    lv[2 * j + 1] = (short)(hi >> 16);
                }
                int off = row * 64 + ((ch ^ (row & 7)) << 3);
                *(short8*)(Vh + off) = hv;
                *(short8*)(Vl + off) = lv;
            }
        }
        __syncthreads();

        // A fragments direct from xT (read-only, L2-cached)
        short8 ah[2][2], al[2][2];
#pragma unroll
        for (int ks = 0; ks < 2; ++ks)
#pragma unroll
            for (int mt = 0; mt < 2; ++mt) {
                size_t ga = (size_t)(m0 + w * 32 + mt * 16 + l15) * B
                          + k0 + (ks << 5) + (q << 3);
                ah[ks][mt] = *(const short8*)(xTh + ga);
                al[ks][mt] = *(const short8*)(xTl + ga);
            }

#pragma unroll
        for (int ks = 0; ks < 2; ++ks) {
#pragma unroll
            for (int nt = 0; nt < 5; ++nt) {
                int rn  = nt * 16 + l15;
                int off = rn * 64 + ((((ks << 2) + q) ^ (rn & 7)) << 3);
                short8 bh = *(const short8*)(Vh + off);
                short8 bl = *(const short8*)(Vl + off);
#pragma unroll
                for (int mt = 0; mt < 2; ++mt) {
                    acc[mt][nt] = __builtin_amdgcn_mfma_f32_16x16x32_bf16(ah[ks][mt], bh, acc[mt][nt], 0, 0, 0);
                    acc[mt][nt] = __builtin_amdgcn_mfma_f32_16x16x32_bf16(ah[ks][mt], bl, acc[mt][nt], 0, 0, 0);
                    acc[mt][nt] = __builtin_amdgcn_mfma_f32_16x16x32_bf16(al[ks][mt], bh, acc[mt][nt], 0, 0, 0);
                }
            }
        }
    }

    // agree epilogue: acc[mt][nt][reg] = G[i = rb>>3][d = (rb&7)+reg][oe]
#pragma unroll
    for (int mt = 0; mt < 2; ++mt) {
        int rb = m0 + w * 32 + mt * 16 + q * 4;
        int i  = rb >> 3;
        int d0 = rb & 7;                          // 0 or 4 (q parity)
#pragma unroll
        for (int nt = 0; nt < 5; ++nt) {
            int oe = oe0 + nt * 16 + l15;
            float4 wv = *(const float4*)(Wt + (size_t)i * WROW + oe * 8 + d0);
            floatx4 a = acc[mt][nt];
            float p = a[0] * wv.x + a[1] * wv.y + a[2] * wv.z + a[3] * wv.w;
            p += __shfl_xor(p, 1);                 // e-lanes
            p += __shfl_xor(p, 2);
            p += __shfl_xor(p, 4);
            p += __shfl_xor(p, 8);
            p += __shfl_xor(p, 16);                // d-halves (q pairs)
            if ((lane & 31) == 0)
                AS(&agree[i * O + nb * 5 + nt], p);
        }
    }
}

// ---------------------------------------------------------------------------
// MEGA kernel: whole pipeline; 1 fenced barrier + 7 light barriers.
// ---------------------------------------------------------------------------
__global__ __launch_bounds__(256, 2) void mega_kernel(
    const float* __restrict__ x, const float* __restrict__ W,
    float* __restrict__ out, float* __restrict__ Wt,
    unsigned short* __restrict__ xTh, unsigned short* __restrict__ xTl,
    unsigned short* __restrict__ xh,  unsigned short* __restrict__ xl,
    unsigned* __restrict__ vT,
    float* __restrict__ sp, float* __restrict__ a0, float* __restrict__ a1,
    unsigned* __restrict__ bar)
{
    __shared__ unsigned short Sh[80 * 64], Sl[80 * 64];   // spart & ggemm reuse
    __shared__ float brow_s[16][10];
    __shared__ float cL[16][10];

    unsigned* cnt = bar;            // cacheline 0
    unsigned* gen = bar + 32;       // cacheline 1
    int bid = blockIdx.x;
    int t   = threadIdx.x;

    stage_prep(bid, t, x, W, Wt, xTh, xTl, xh, xl);
    gbar_full(cnt, gen);            // one-time: flush plain-stored prep data

    for (int it = 0; it < 3; ++it) {
        stage_spart(bid, t, Sh, Sl, brow_s, cL, xh, xl, Wt, a0, a1, sp, it);
        gbar_light(cnt, gen);
        stage_vred(bid, t, sp, out, vT, it == 2);
        if (it == 2) break;
        gbar_light(cnt, gen);
        stage_ggemm(bid, t, Sh, Sl, xTh, xTl, vT, Wt, it == 0 ? a0 : a1);
        gbar_light(cnt, gen);
    }
}

// ---------------------------------------------------------------------------
extern "C" void kernel_launch(void* const* d_in, const int* in_sizes, int n_in,
                              void* d_out, int out_size, void* d_ws, size_t ws_size,
                              hipStream_t stream)
{
    const float* x = (const float*)d_in[0];   // [256,1152,8]
    const float* W = (const float*)d_in[1];   // [1152,10,8,16]
    float* out = (float*)d_out;               // [256,10,16,1] flat = 40960

    // ws: bar 256B | a0 | a1 | Wt 5.9MB | sp 11.8MB | xTh/xTl 9.4MB |
    //     xh/xl 9.4MB | vT 160KB        (~37 MB of 256 MB)
    unsigned* bar = (unsigned*)d_ws;
    float* a0 = (float*)((char*)d_ws + 256);
    float* a1 = a0 + I * O;
    float* Wt = a1 + I * O;
    float* sp = Wt + (size_t)I * OE * DIN;
    unsigned short* xTh = (unsigned short*)(sp + (size_t)PSPLIT * B * OE);
    unsigned short* xTl = xTh + (size_t)XROW * B;
    unsigned short* xh  = xTl + (size_t)XROW * B;
    unsigned short* xl  = xh  + (size_t)XROW * B;
    unsigned* vT        = (unsigned*)(xl + (size_t)XROW * B);

    // zero barrier state (memset node is graph-capture legal)
    hipMemsetAsync(d_ws, 0, 256, stream);

    mega_kernel<<<GRID, 256, 0, stream>>>(
        x, W, out, Wt, xTh, xTl, xh, xl, vT, sp, a0, a1, bar);
}